// Round 1
// baseline (1138.593 us; speedup 1.0000x reference)
//
#include <hip/hip_runtime.h>
#include <hip/hip_bf16.h>
#include <math.h>

#define NV 32000
#define NE 50
#define NH 100
#define NB 8
#define NT 512

// ---------------------------------------------------------------------------
// Kernel 1: embed + input projections.  Xg[t][b][j] = b_g[j] + sum_e x[e]*W_xg[e][j]
// ---------------------------------------------------------------------------
__global__ __launch_bounds__(128) void xproj_kernel(
    const int* __restrict__ inp, const float* __restrict__ emb,
    const float* __restrict__ Wxr, const float* __restrict__ br,
    const float* __restrict__ Wxz, const float* __restrict__ bz,
    const float* __restrict__ Wxh, const float* __restrict__ bh,
    float* __restrict__ Xr, float* __restrict__ Xz, float* __restrict__ Xh)
{
    int n = blockIdx.x;            // n = t*NB + b
    int t = n >> 3, b = n & 7;
    __shared__ float xs[NE];
    int tid = threadIdx.x;
    int idx = inp[b * NT + t];
    if (tid < NE) xs[tid] = emb[idx * NE + tid];
    __syncthreads();
    if (tid < NH) {
        float ar = br[tid], az = bz[tid], ah = bh[tid];
        for (int e = 0; e < NE; e++) {
            float x = xs[e];
            ar += x * Wxr[e * NH + tid];
            az += x * Wxz[e * NH + tid];
            ah += x * Wxh[e * NH + tid];
        }
        Xr[n * NH + tid] = ar;
        Xz[n * NH + tid] = az;
        Xh[n * NH + tid] = ah;
    }
}

// ---------------------------------------------------------------------------
// Kernel 2: sequential GRU recurrence. One block per batch.
// 3 gate-groups of 128 threads; thread j of group g holds W_g column j in regs.
// ---------------------------------------------------------------------------
__global__ __launch_bounds__(384) void gru_rec_kernel(
    const float* __restrict__ Whr, const float* __restrict__ Whz,
    const float* __restrict__ Whh,
    const float* __restrict__ Xr, const float* __restrict__ Xz,
    const float* __restrict__ Xh, float* __restrict__ Hall)
{
    int b   = blockIdx.x;          // 0..7
    int tid = threadIdx.x;
    int g   = tid >> 7;            // gate group: 0=R, 1=Z, 2=Htilda
    int j   = tid & 127;

    __shared__ __align__(16) float h_s[104];
    __shared__ __align__(16) float rh_s[104];
    __shared__ float z_s[104];

    const float* W  = (g == 0) ? Whr : (g == 1) ? Whz : Whh;
    const float* Xg = (g == 0) ? Xr  : (g == 1) ? Xz  : Xh;

    float w[NH];
    if (j < NH) {
        #pragma unroll
        for (int k = 0; k < NH; k++) w[k] = W[k * NH + j];
    }
    if (tid < NH) h_s[tid] = 0.0f;
    __syncthreads();

    float x_cur = (j < NH) ? Xg[b * NH + j] : 0.0f;   // t = 0

    const float4* h4  = (const float4*)h_s;
    const float4* rh4 = (const float4*)rh_s;

    for (int t = 0; t < NT; t++) {
        float x_next = 0.0f;
        if (t + 1 < NT && j < NH) x_next = Xg[((t + 1) * NB + b) * NH + j];

        if (g <= 1 && j < NH) {
            float a0 = x_cur, a1 = 0.f, a2 = 0.f, a3 = 0.f;
            #pragma unroll
            for (int kk = 0; kk < NH / 4; kk++) {
                float4 hv = h4[kk];
                a0 += hv.x * w[4 * kk + 0];
                a1 += hv.y * w[4 * kk + 1];
                a2 += hv.z * w[4 * kk + 2];
                a3 += hv.w * w[4 * kk + 3];
            }
            float acc = (a0 + a1) + (a2 + a3);
            float s = 1.0f / (1.0f + __expf(-acc));
            if (g == 0) rh_s[j] = s * h_s[j];
            else        z_s[j]  = s;
        }
        __syncthreads();
        if (g == 2 && j < NH) {
            float a0 = x_cur, a1 = 0.f, a2 = 0.f, a3 = 0.f;
            #pragma unroll
            for (int kk = 0; kk < NH / 4; kk++) {
                float4 hv = rh4[kk];
                a0 += hv.x * w[4 * kk + 0];
                a1 += hv.y * w[4 * kk + 1];
                a2 += hv.z * w[4 * kk + 2];
                a3 += hv.w * w[4 * kk + 3];
            }
            float acc = (a0 + a1) + (a2 + a3);
            float ht = tanhf(acc);
            float z  = z_s[j];
            float hn = z * ht + (1.0f - z) * h_s[j];
            h_s[j] = hn;
            Hall[(t * NB + b) * NH + j] = hn;
        }
        __syncthreads();
        x_cur = x_next;
    }
}

// ---------------------------------------------------------------------------
// Kernel 3: output GEMM  Y[n][v] = Hall[n][:] @ fcW[:][v] + fcb[v]
// Block: 16 rows x 1024 cols, 256 threads, each thread 16 rows x 4 cols.
// ---------------------------------------------------------------------------
__global__ __launch_bounds__(256) void outgemm_kernel(
    const float* __restrict__ Hall, const float* __restrict__ fcW,
    const float* __restrict__ fcb, float* __restrict__ out)
{
    __shared__ __align__(16) float ht[NH][16];
    int tid = threadIdx.x;
    int n0  = blockIdx.x * 16;

    // load H tile transposed: ht[k][r] = Hall[(n0+r)][k]; global coalesced.
    for (int i = tid; i < 16 * NH; i += 256) {
        int r = i / NH, k = i - r * NH;
        ht[k][r] = Hall[(n0 + r) * NH + k];
    }
    __syncthreads();

    int c = blockIdx.y * 1024 + tid * 4;
    if (c >= NV) return;

    float4 acc[16];
    #pragma unroll
    for (int r = 0; r < 16; r++) acc[r] = make_float4(0.f, 0.f, 0.f, 0.f);

    const float4* Wv = (const float4*)fcW;
    int cq = c >> 2;

    #pragma unroll 2
    for (int k = 0; k < NH; k++) {
        float4 wv = Wv[k * (NV / 4) + cq];
        float4 h0 = *(const float4*)&ht[k][0];
        float4 h1 = *(const float4*)&ht[k][4];
        float4 h2 = *(const float4*)&ht[k][8];
        float4 h3 = *(const float4*)&ht[k][12];
        float hs[16] = { h0.x, h0.y, h0.z, h0.w,
                         h1.x, h1.y, h1.z, h1.w,
                         h2.x, h2.y, h2.z, h2.w,
                         h3.x, h3.y, h3.z, h3.w };
        #pragma unroll
        for (int r = 0; r < 16; r++) {
            acc[r].x += hs[r] * wv.x;
            acc[r].y += hs[r] * wv.y;
            acc[r].z += hs[r] * wv.z;
            acc[r].w += hs[r] * wv.w;
        }
    }

    float4 bias = *(const float4*)&fcb[c];
    #pragma unroll
    for (int r = 0; r < 16; r++) {
        int n   = n0 + r;
        int row = ((n & 7) << 9) + (n >> 3);       // b*512 + t
        float4 v;
        v.x = acc[r].x + bias.x;
        v.y = acc[r].y + bias.y;
        v.z = acc[r].z + bias.z;
        v.w = acc[r].w + bias.w;
        *(float4*)&out[(size_t)row * NV + c] = v;
    }
}

// ---------------------------------------------------------------------------
extern "C" void kernel_launch(void* const* d_in, const int* in_sizes, int n_in,
                              void* d_out, int out_size, void* d_ws, size_t ws_size,
                              hipStream_t stream)
{
    const int*   inp = (const int*)  d_in[0];
    const float* emb = (const float*)d_in[1];
    const float* Whr = (const float*)d_in[2];
    const float* Wxr = (const float*)d_in[3];
    const float* br  = (const float*)d_in[4];
    const float* Whz = (const float*)d_in[5];
    const float* Wxz = (const float*)d_in[6];
    const float* bz  = (const float*)d_in[7];
    const float* Whh = (const float*)d_in[8];
    const float* Wxh = (const float*)d_in[9];
    const float* bh  = (const float*)d_in[10];
    const float* fcW = (const float*)d_in[11];
    const float* fcb = (const float*)d_in[12];
    float* out = (float*)d_out;

    float* Xr   = (float*)d_ws;
    float* Xz   = Xr + NT * NB * NH;
    float* Xh   = Xz + NT * NB * NH;
    float* Hall = Xh + NT * NB * NH;

    xproj_kernel<<<NT * NB, 128, 0, stream>>>(inp, emb, Wxr, br, Wxz, bz, Wxh, bh,
                                              Xr, Xz, Xh);
    gru_rec_kernel<<<NB, 384, 0, stream>>>(Whr, Whz, Whh, Xr, Xz, Xh, Hall);
    dim3 ggrid(NT * NB / 16, (NV + 1023) / 1024);
    outgemm_kernel<<<ggrid, 256, 0, stream>>>(Hall, fcW, fcb, out);
}

// Round 3
// 859.158 us; speedup vs baseline: 1.3252x; 1.3252x over previous
//
#include <hip/hip_runtime.h>
#include <hip/hip_bf16.h>
#include <math.h>

#define NV 32000
#define NE 50
#define NH 100
#define NB 8
#define NT 512
#define CH 8

// LDS-only barrier, race-free:
//  - pre-barrier memory-clobber asm + lgkmcnt(0): LDS writes cannot sink past
//    it, and are drained before the rendezvous.
//  - post-barrier empty memory-clobber asm: LDS reads cannot hoist above it
//    (bare s_barrier is IntrNoMem in LLVM -> loads may otherwise cross it).
//  Global loads/stores (vmcnt) stay in flight across the barrier.
__device__ __forceinline__ void bar_lgkm() {
    __builtin_amdgcn_sched_barrier(0);
    asm volatile("s_waitcnt lgkmcnt(0)" ::: "memory");
    __builtin_amdgcn_s_barrier();
    asm volatile("" ::: "memory");
    __builtin_amdgcn_sched_barrier(0);
}

// ---------------------------------------------------------------------------
// Kernel 1: embed + input projections.  Xg[t][b][j] = b_g[j] + sum_e x[e]*W_xg[e][j]
// ---------------------------------------------------------------------------
__global__ __launch_bounds__(128) void xproj_kernel(
    const int* __restrict__ inp, const float* __restrict__ emb,
    const float* __restrict__ Wxr, const float* __restrict__ br,
    const float* __restrict__ Wxz, const float* __restrict__ bz,
    const float* __restrict__ Wxh, const float* __restrict__ bh,
    float* __restrict__ Xr, float* __restrict__ Xz, float* __restrict__ Xh)
{
    int n = blockIdx.x;            // n = t*NB + b
    int t = n >> 3, b = n & 7;
    __shared__ float xs[NE];
    int tid = threadIdx.x;
    int idx = inp[b * NT + t];
    if (tid < NE) xs[tid] = emb[idx * NE + tid];
    __syncthreads();
    if (tid < NH) {
        float ar = br[tid], az = bz[tid], ah = bh[tid];
        for (int e = 0; e < NE; e++) {
            float x = xs[e];
            ar += x * Wxr[e * NH + tid];
            az += x * Wxz[e * NH + tid];
            ah += x * Wxh[e * NH + tid];
        }
        Xr[n * NH + tid] = ar;
        Xz[n * NH + tid] = az;
        Xh[n * NH + tid] = ah;
    }
}

// ---------------------------------------------------------------------------
// Kernel 2: sequential GRU recurrence. One block per batch, 768 threads.
// 3 gate groups (R,Z,Htilda) x 4 waves. Output j handled by lane pair
// (l, l+32) of one wave, each holding a 52-element K-half of W's column j
// in registers; partials combined with one __shfl_xor(32). LDS-only
// barriers; x prefetched one 8-step chunk ahead (double-buffered regs).
// ---------------------------------------------------------------------------
__global__ __launch_bounds__(768, 3) void gru_rec_kernel(
    const float* __restrict__ Whr, const float* __restrict__ Whz,
    const float* __restrict__ Whh,
    const float* __restrict__ Xr, const float* __restrict__ Xz,
    const float* __restrict__ Xh, float* __restrict__ Hall)
{
    int b   = blockIdx.x;          // 0..7
    int tid = threadIdx.x;
    int g   = tid >> 8;            // gate group: 0=R, 1=Z, 2=Htilda
    int u   = tid & 255;
    int q   = u >> 6;              // wave within group 0..3
    int l   = u & 63;
    int jj  = q * 32 + (l & 31);   // output index 0..127 (valid < 100)
    int kh  = l >> 5;              // K-half: 0 -> k 0..51, 1 -> k 52..103
    int kbase = kh * 52;
    int jc  = (jj < NH) ? jj : 0;
    bool act = (kh == 0) && (jj < NH);

    __shared__ __align__(16) float h_s[104];
    __shared__ __align__(16) float rh_s[104];
    __shared__ __align__(16) float z_s[104];

    const float* W  = (g == 0) ? Whr : (g == 1) ? Whz : Whh;
    const float* Xg = (g == 0) ? Xr  : (g == 1) ? Xz  : Xh;

    float w[52];
    #pragma unroll
    for (int m = 0; m < 52; m++) {
        int k = kbase + m;
        w[m] = (jj < NH && k < NH) ? W[k * NH + jj] : 0.0f;
    }
    if (tid < 104) { h_s[tid] = 0.0f; rh_s[tid] = 0.0f; z_s[tid] = 0.0f; }
    __syncthreads();

    float xb_cur[CH], xb_nxt[CH];
    if (act) {
        #pragma unroll
        for (int i = 0; i < CH; i++)
            xb_cur[i] = Xg[(i * NB + b) * NH + jj];
    }

    for (int tc = 0; tc < NT; tc += CH) {
        if (act && tc + CH < NT) {
            #pragma unroll
            for (int i = 0; i < CH; i++)
                xb_nxt[i] = Xg[((tc + CH + i) * NB + b) * NH + jj];
        }
        #pragma unroll
        for (int i = 0; i < CH; i++) {
            int t = tc + i;
            if (g < 2) {
                float hj = h_s[jc];
                float a0 = 0.f, a1 = 0.f, a2 = 0.f, a3 = 0.f;
                const float4* hv4 = (const float4*)h_s + kh * 13;
                #pragma unroll
                for (int kk = 0; kk < 13; kk++) {
                    float4 hv = hv4[kk];
                    a0 += hv.x * w[4 * kk + 0];
                    a1 += hv.y * w[4 * kk + 1];
                    a2 += hv.z * w[4 * kk + 2];
                    a3 += hv.w * w[4 * kk + 3];
                }
                float part = (a0 + a1) + (a2 + a3);
                float tot  = part + __shfl_xor(part, 32, 64);
                if (act) {
                    float s = 1.0f / (1.0f + __expf(-(tot + xb_cur[i])));
                    if (g == 0) rh_s[jj] = s * hj;
                    else        z_s[jj]  = s;
                }
            }
            bar_lgkm();                    // rh_s, z_s visible
            if (g == 2) {
                float a0 = 0.f, a1 = 0.f, a2 = 0.f, a3 = 0.f;
                const float4* rv4 = (const float4*)rh_s + kh * 13;
                #pragma unroll
                for (int kk = 0; kk < 13; kk++) {
                    float4 rv = rv4[kk];
                    a0 += rv.x * w[4 * kk + 0];
                    a1 += rv.y * w[4 * kk + 1];
                    a2 += rv.z * w[4 * kk + 2];
                    a3 += rv.w * w[4 * kk + 3];
                }
                float part = (a0 + a1) + (a2 + a3);
                float tot  = part + __shfl_xor(part, 32, 64);
                if (act) {
                    float a  = tot + xb_cur[i];
                    float e  = __expf(2.0f * a);
                    float ht = 1.0f - 2.0f / (e + 1.0f);   // tanh(a)
                    float z  = z_s[jc], h = h_s[jc];
                    float hn = fmaf(z, ht - h, h);         // z*ht + (1-z)*h
                    h_s[jj] = hn;
                    Hall[(t * NB + b) * NH + jj] = hn;
                }
            }
            bar_lgkm();                    // h_s visible
        }
        if (act) {
            #pragma unroll
            for (int i = 0; i < CH; i++) xb_cur[i] = xb_nxt[i];
        }
    }
}

// ---------------------------------------------------------------------------
// Kernel 3: output GEMM  Y[n][v] = Hall[n][:] @ fcW[:][v] + fcb[v]
// Block: 16 rows x 1024 cols, 256 threads, each thread 16 rows x 4 cols.
// ---------------------------------------------------------------------------
__global__ __launch_bounds__(256) void outgemm_kernel(
    const float* __restrict__ Hall, const float* __restrict__ fcW,
    const float* __restrict__ fcb, float* __restrict__ out)
{
    __shared__ __align__(16) float ht[NH][16];
    int tid = threadIdx.x;
    int n0  = blockIdx.x * 16;

    for (int i = tid; i < 16 * NH; i += 256) {
        int r = i / NH, k = i - r * NH;
        ht[k][r] = Hall[(n0 + r) * NH + k];
    }
    __syncthreads();

    int c = blockIdx.y * 1024 + tid * 4;
    if (c >= NV) return;

    float4 acc[16];
    #pragma unroll
    for (int r = 0; r < 16; r++) acc[r] = make_float4(0.f, 0.f, 0.f, 0.f);

    const float4* Wv = (const float4*)fcW;
    int cq = c >> 2;

    #pragma unroll 2
    for (int k = 0; k < NH; k++) {
        float4 wv = Wv[k * (NV / 4) + cq];
        float4 h0 = *(const float4*)&ht[k][0];
        float4 h1 = *(const float4*)&ht[k][4];
        float4 h2 = *(const float4*)&ht[k][8];
        float4 h3 = *(const float4*)&ht[k][12];
        float hs[16] = { h0.x, h0.y, h0.z, h0.w,
                         h1.x, h1.y, h1.z, h1.w,
                         h2.x, h2.y, h2.z, h2.w,
                         h3.x, h3.y, h3.z, h3.w };
        #pragma unroll
        for (int r = 0; r < 16; r++) {
            acc[r].x += hs[r] * wv.x;
            acc[r].y += hs[r] * wv.y;
            acc[r].z += hs[r] * wv.z;
            acc[r].w += hs[r] * wv.w;
        }
    }

    float4 bias = *(const float4*)&fcb[c];
    #pragma unroll
    for (int r = 0; r < 16; r++) {
        int n   = n0 + r;
        int row = ((n & 7) << 9) + (n >> 3);       // b*512 + t
        float4 v;
        v.x = acc[r].x + bias.x;
        v.y = acc[r].y + bias.y;
        v.z = acc[r].z + bias.z;
        v.w = acc[r].w + bias.w;
        *(float4*)&out[(size_t)row * NV + c] = v;
    }
}

// ---------------------------------------------------------------------------
extern "C" void kernel_launch(void* const* d_in, const int* in_sizes, int n_in,
                              void* d_out, int out_size, void* d_ws, size_t ws_size,
                              hipStream_t stream)
{
    const int*   inp = (const int*)  d_in[0];
    const float* emb = (const float*)d_in[1];
    const float* Whr = (const float*)d_in[2];
    const float* Wxr = (const float*)d_in[3];
    const float* br  = (const float*)d_in[4];
    const float* Whz = (const float*)d_in[5];
    const float* Wxz = (const float*)d_in[6];
    const float* bz  = (const float*)d_in[7];
    const float* Whh = (const float*)d_in[8];
    const float* Wxh = (const float*)d_in[9];
    const float* bh  = (const float*)d_in[10];
    const float* fcW = (const float*)d_in[11];
    const float* fcb = (const float*)d_in[12];
    float* out = (float*)d_out;

    float* Xr   = (float*)d_ws;
    float* Xz   = Xr + NT * NB * NH;
    float* Xh   = Xz + NT * NB * NH;
    float* Hall = Xh + NT * NB * NH;

    xproj_kernel<<<NT * NB, 128, 0, stream>>>(inp, emb, Wxr, br, Wxz, bz, Wxh, bh,
                                              Xr, Xz, Xh);
    gru_rec_kernel<<<NB, 768, 0, stream>>>(Whr, Whz, Whh, Xr, Xz, Xh, Hall);
    dim3 ggrid(NT * NB / 16, (NV + 1023) / 1024);
    outgemm_kernel<<<ggrid, 256, 0, stream>>>(Hall, fcW, fcb, out);
}

// Round 4
// 611.246 us; speedup vs baseline: 1.8627x; 1.4056x over previous
//
#include <hip/hip_runtime.h>
#include <hip/hip_bf16.h>
#include <hip/hip_fp16.h>
#include <math.h>

#define NV 32000
#define NE 50
#define NH 100
#define NB 8
#define NT 512
#define CH 8
#define KP 112   // K padded to 7 k-tiles of 16 for mfma_32x32x16

typedef __attribute__((ext_vector_type(8)))  _Float16 f16x8;
typedef __attribute__((ext_vector_type(16))) float    f32x16;

// LDS-only barrier, race-free (see R3 post-mortem): pre-barrier clobber+lgkmcnt
// pins LDS writes before the rendezvous; post-barrier clobber pins reads after.
__device__ __forceinline__ void bar_lgkm() {
    __builtin_amdgcn_sched_barrier(0);
    asm volatile("s_waitcnt lgkmcnt(0)" ::: "memory");
    __builtin_amdgcn_s_barrier();
    asm volatile("" ::: "memory");
    __builtin_amdgcn_sched_barrier(0);
}

// ---------------------------------------------------------------------------
// Kernel 0: fc_W f32 [k][v]  ->  fp16 MFMA-B-fragment order:
// Wp[((ct*7+kt)*64 + l)*8 + j] = W[kt*16+(l>>5)*8+j][ct*32+(l&31)]  (0 if k>=100)
// ---------------------------------------------------------------------------
__global__ __launch_bounds__(256) void convw_kernel(
    const float* __restrict__ W, _Float16* __restrict__ Wp)
{
    int wv = threadIdx.x >> 6, l = threadIdx.x & 63;
    int ct = blockIdx.x * 4 + wv;
    int v  = ct * 32 + (l & 31);
    int kb = (l >> 5) * 8;
    _Float16* dst = Wp + (size_t)ct * 7 * 512 + l * 8;
    for (int kt = 0; kt < 7; kt++) {
        f16x8 tmp;
        #pragma unroll
        for (int j = 0; j < 8; j++) {
            int k = kt * 16 + kb + j;
            tmp[j] = (_Float16)(k < NH ? W[(size_t)k * NV + v] : 0.0f);
        }
        *(f16x8*)(dst + (size_t)kt * 512) = tmp;
    }
}

// ---------------------------------------------------------------------------
// Kernel 1: embed + input projections.  Xg[t][b][j] = b_g[j] + sum_e x[e]*W_xg[e][j]
// ---------------------------------------------------------------------------
__global__ __launch_bounds__(128) void xproj_kernel(
    const int* __restrict__ inp, const float* __restrict__ emb,
    const float* __restrict__ Wxr, const float* __restrict__ br,
    const float* __restrict__ Wxz, const float* __restrict__ bz,
    const float* __restrict__ Wxh, const float* __restrict__ bh,
    float* __restrict__ Xr, float* __restrict__ Xz, float* __restrict__ Xh)
{
    int n = blockIdx.x;            // n = t*NB + b
    int t = n >> 3, b = n & 7;
    __shared__ float xs[NE];
    int tid = threadIdx.x;
    int idx = inp[b * NT + t];
    if (tid < NE) xs[tid] = emb[idx * NE + tid];
    __syncthreads();
    if (tid < NH) {
        float ar = br[tid], az = bz[tid], ah = bh[tid];
        for (int e = 0; e < NE; e++) {
            float x = xs[e];
            ar += x * Wxr[e * NH + tid];
            az += x * Wxz[e * NH + tid];
            ah += x * Wxh[e * NH + tid];
        }
        Xr[n * NH + tid] = ar;
        Xz[n * NH + tid] = az;
        Xh[n * NH + tid] = ah;
    }
}

// ---------------------------------------------------------------------------
// Kernel 2: sequential GRU recurrence (verified R3 structure, unchanged math).
// Only change: H is stored as fp16 into K-padded [4096][KP] layout for the
// MFMA out-GEMM (12 zero-pad stores per row), recurrence state stays f32.
// ---------------------------------------------------------------------------
__global__ __launch_bounds__(768, 3) void gru_rec_kernel(
    const float* __restrict__ Whr, const float* __restrict__ Whz,
    const float* __restrict__ Whh,
    const float* __restrict__ Xr, const float* __restrict__ Xz,
    const float* __restrict__ Xh, _Float16* __restrict__ Hp)
{
    int b   = blockIdx.x;          // 0..7
    int tid = threadIdx.x;
    int g   = tid >> 8;            // gate group: 0=R, 1=Z, 2=Htilda
    int u   = tid & 255;
    int q   = u >> 6;              // wave within group 0..3
    int l   = u & 63;
    int jj  = q * 32 + (l & 31);   // output index 0..127 (valid < 100)
    int kh  = l >> 5;              // K-half: 0 -> k 0..51, 1 -> k 52..103
    int kbase = kh * 52;
    int jc  = (jj < NH) ? jj : 0;
    bool act = (kh == 0) && (jj < NH);

    __shared__ __align__(16) float h_s[104];
    __shared__ __align__(16) float rh_s[104];
    __shared__ __align__(16) float z_s[104];

    const float* W  = (g == 0) ? Whr : (g == 1) ? Whz : Whh;
    const float* Xg = (g == 0) ? Xr  : (g == 1) ? Xz  : Xh;

    float w[52];
    #pragma unroll
    for (int m = 0; m < 52; m++) {
        int k = kbase + m;
        w[m] = (jj < NH && k < NH) ? W[k * NH + jj] : 0.0f;
    }
    if (tid < 104) { h_s[tid] = 0.0f; rh_s[tid] = 0.0f; z_s[tid] = 0.0f; }
    __syncthreads();

    float xb_cur[CH], xb_nxt[CH];
    if (act) {
        #pragma unroll
        for (int i = 0; i < CH; i++)
            xb_cur[i] = Xg[(i * NB + b) * NH + jj];
    }

    for (int tc = 0; tc < NT; tc += CH) {
        if (act && tc + CH < NT) {
            #pragma unroll
            for (int i = 0; i < CH; i++)
                xb_nxt[i] = Xg[((tc + CH + i) * NB + b) * NH + jj];
        }
        #pragma unroll
        for (int i = 0; i < CH; i++) {
            int t = tc + i;
            if (g < 2) {
                float hj = h_s[jc];
                float a0 = 0.f, a1 = 0.f, a2 = 0.f, a3 = 0.f;
                const float4* hv4 = (const float4*)h_s + kh * 13;
                #pragma unroll
                for (int kk = 0; kk < 13; kk++) {
                    float4 hv = hv4[kk];
                    a0 += hv.x * w[4 * kk + 0];
                    a1 += hv.y * w[4 * kk + 1];
                    a2 += hv.z * w[4 * kk + 2];
                    a3 += hv.w * w[4 * kk + 3];
                }
                float part = (a0 + a1) + (a2 + a3);
                float tot  = part + __shfl_xor(part, 32, 64);
                if (act) {
                    float s = 1.0f / (1.0f + __expf(-(tot + xb_cur[i])));
                    if (g == 0) rh_s[jj] = s * hj;
                    else        z_s[jj]  = s;
                }
            }
            bar_lgkm();                    // rh_s, z_s visible
            if (g == 2) {
                float a0 = 0.f, a1 = 0.f, a2 = 0.f, a3 = 0.f;
                const float4* rv4 = (const float4*)rh_s + kh * 13;
                #pragma unroll
                for (int kk = 0; kk < 13; kk++) {
                    float4 rv = rv4[kk];
                    a0 += rv.x * w[4 * kk + 0];
                    a1 += rv.y * w[4 * kk + 1];
                    a2 += rv.z * w[4 * kk + 2];
                    a3 += rv.w * w[4 * kk + 3];
                }
                float part = (a0 + a1) + (a2 + a3);
                float tot  = part + __shfl_xor(part, 32, 64);
                if (act) {
                    float a  = tot + xb_cur[i];
                    float e  = __expf(2.0f * a);
                    float ht = 1.0f - 2.0f / (e + 1.0f);   // tanh(a)
                    float z  = z_s[jc], h = h_s[jc];
                    float hn = fmaf(z, ht - h, h);         // z*ht + (1-z)*h
                    h_s[jj] = hn;
                    size_t n2 = (size_t)(t * NB + b) * KP;
                    Hp[n2 + jj] = (_Float16)hn;
                    if (jj < KP - NH) Hp[n2 + NH + jj] = (_Float16)0.0f;
                }
            }
            bar_lgkm();                    // h_s visible
        }
        if (act) {
            #pragma unroll
            for (int i = 0; i < CH; i++) xb_cur[i] = xb_nxt[i];
        }
    }
}

// ---------------------------------------------------------------------------
// Kernel 3: out-GEMM via fp16 MFMA.  C[4096][32000] = Hp @ Wp + fcb.
// Block 256 thr = 4 waves; tile M=32 (shared), N=256 (64 cols/wave = 2 ct).
// Per wave: 7 A-frags (held), 2x7 B-frags streamed, 14 mfma_f32_32x32x16_f16.
// A: lane row=l&31, k=(l>>5)*8+j.  B: col=l&31, same k.  D: col=l&31,
// row=(p&3)+8*(p>>2)+4*(l>>5).  Output row remap n=t*8+b -> b*512+t.
// ---------------------------------------------------------------------------
__global__ __launch_bounds__(256) void outgemm_kernel(
    const _Float16* __restrict__ Hp, const _Float16* __restrict__ Wp,
    const float* __restrict__ fcb, float* __restrict__ out)
{
    int tid = threadIdx.x;
    int wv = tid >> 6, l = tid & 63;
    int n0 = blockIdx.x * 32;
    int cb = blockIdx.y * 256 + wv * 64;

    const _Float16* arow = Hp + (size_t)(n0 + (l & 31)) * KP + (l >> 5) * 8;
    f16x8 a[7];
    #pragma unroll
    for (int kt = 0; kt < 7; kt++)
        a[kt] = *(const f16x8*)(arow + kt * 16);

    int ct0 = cb >> 5;
    const _Float16* bp = Wp + (size_t)ct0 * 7 * 512 + l * 8;

    f32x16 acc0 = {0,0,0,0,0,0,0,0,0,0,0,0,0,0,0,0};
    f32x16 acc1 = {0,0,0,0,0,0,0,0,0,0,0,0,0,0,0,0};
    #pragma unroll
    for (int kt = 0; kt < 7; kt++) {
        f16x8 b0 = *(const f16x8*)(bp + (size_t)kt * 512);
        f16x8 b1 = *(const f16x8*)(bp + (size_t)(kt + 7) * 512);
        acc0 = __builtin_amdgcn_mfma_f32_32x32x16_f16(a[kt], b0, acc0, 0, 0, 0);
        acc1 = __builtin_amdgcn_mfma_f32_32x32x16_f16(a[kt], b1, acc1, 0, 0, 0);
    }

    int c0 = cb + (l & 31);
    float bias0 = fcb[c0], bias1 = fcb[c0 + 32];
    #pragma unroll
    for (int p = 0; p < 16; p++) {
        int r = (p & 3) + 8 * (p >> 2) + 4 * (l >> 5);
        int m = n0 + r;
        size_t row = (size_t)(m & 7) * NT + (m >> 3);   // b*512 + t
        out[row * NV + c0]      = acc0[p] + bias0;
        out[row * NV + c0 + 32] = acc1[p] + bias1;
    }
}

// ---------------------------------------------------------------------------
extern "C" void kernel_launch(void* const* d_in, const int* in_sizes, int n_in,
                              void* d_out, int out_size, void* d_ws, size_t ws_size,
                              hipStream_t stream)
{
    const int*   inp = (const int*)  d_in[0];
    const float* emb = (const float*)d_in[1];
    const float* Whr = (const float*)d_in[2];
    const float* Wxr = (const float*)d_in[3];
    const float* br  = (const float*)d_in[4];
    const float* Whz = (const float*)d_in[5];
    const float* Wxz = (const float*)d_in[6];
    const float* bz  = (const float*)d_in[7];
    const float* Whh = (const float*)d_in[8];
    const float* Wxh = (const float*)d_in[9];
    const float* bh  = (const float*)d_in[10];
    const float* fcW = (const float*)d_in[11];
    const float* fcb = (const float*)d_in[12];
    float* out = (float*)d_out;

    float*    Xr = (float*)d_ws;                       // [NT*NB*NH] f32
    float*    Xz = Xr + NT * NB * NH;
    float*    Xh = Xz + NT * NB * NH;
    _Float16* Hp = (_Float16*)(Xh + NT * NB * NH);     // [NT*NB][KP] fp16
    _Float16* Wp = Hp + (size_t)NT * NB * KP;          // [1000*7*512] fp16

    convw_kernel<<<NV / 32 / 4, 256, 0, stream>>>(fcW, Wp);
    xproj_kernel<<<NT * NB, 128, 0, stream>>>(inp, emb, Wxr, br, Wxz, bz, Wxh, bh,
                                              Xr, Xz, Xh);
    gru_rec_kernel<<<NB, 768, 0, stream>>>(Whr, Whz, Whh, Xr, Xz, Xh, Hp);
    dim3 ggrid(NT * NB / 32, NV / 256);
    outgemm_kernel<<<ggrid, 256, 0, stream>>>(Hp, Wp, fcb, out);
}